// Round 4
// baseline (1187.181 us; speedup 1.0000x reference)
//
#include <hip/hip_runtime.h>
#include <math.h>

#define E_TOTAL   1000000
#define HDIM      128
#define K1        256   // 2H
#define N1        512   // 4H
#define N2        128   // H
#define M_TILE    32
#define BLOCK     256

typedef _Float16 f16;
typedef _Float16 f16_4  __attribute__((ext_vector_type(4)));
typedef _Float16 f16_8  __attribute__((ext_vector_type(8)));
typedef float    f32_16 __attribute__((ext_vector_type(16)));

// ---------------- prep kernels ----------------
// 32x32x16 fragment packing:
// A/B frag layout: lane l holds elem [row=l&31][k=(l>>5)*8+v], v=0..7
// W1F[nt(16)][kc(16)][lane(64)][v(8)] = W1[k=kc*16+(l>>5)*8+v][n=nt*32+(l&31)]
// W2F[nt(4)][kcg(32)][lane(64)][v(8)] = W2[k=kcg*16+(l>>5)*8+v][n=nt*32+(l&31)]
__global__ void prep_weights(const float* __restrict__ W1, const float* __restrict__ W2,
                             f16* __restrict__ W1F, f16* __restrict__ W2F) {
    int t = blockIdx.x * blockDim.x + threadIdx.x;
    const int total1 = K1 * N1;           // 131072
    const int total2 = N1 * N2;           // 65536
    if (t < total1) {
        int v    = t & 7;
        int lane = (t >> 3) & 63;
        int kc   = (t >> 9) & 15;
        int nt   = t >> 13;
        int k = kc * 16 + (lane >> 5) * 8 + v;
        int n = nt * 32 + (lane & 31);
        W1F[t] = (f16)W1[k * N1 + n];
    } else if (t < total1 + total2) {
        int u = t - total1;
        int v    = u & 7;
        int lane = (u >> 3) & 63;
        int kcg  = (u >> 9) & 31;
        int nt   = u >> 14;
        int k = kcg * 16 + (lane >> 5) * 8 + v;
        int n = nt * 32 + (lane & 31);
        W2F[u] = (f16)W2[k * N2 + n];
    }
}

__global__ void prep_emb(const float* __restrict__ emb, f16* __restrict__ emb16) {
    int t = blockIdx.x * blockDim.x + threadIdx.x;   // 3.2M threads, 4 elems each
    float4 f = ((const float4*)emb)[t];
    f16_4 v = { (f16)f.x, (f16)f.y, (f16)f.z, (f16)f.w };
    ((f16_4*)emb16)[t] = v;
}

// ---------------- main kernel ----------------
// 256 threads = 4 waves, 32 edges/block. LDS = 32 KB exactly -> 5 blocks/CU.
// XOR-swizzled LDS at 16B chunks: physical chunk = logical ^ (row&7).
//   sA  [32 edges][256 k] f16 = 16 KB  (reused as sH2 [32][128])
//   sH1 [32 edges][256 wn] f16 = 16 KB (one 256-wide N-half of H1 at a time)
// Wave wv handles P1 n-tiles {hh*8 + wv*2, +1} and P2 n2-tile wv.
template <bool F16EMB>
__global__ __launch_bounds__(BLOCK, 5) void edge_mlp_kernel(
    const float* __restrict__ emb,
    const f16*   __restrict__ emb16,
    const int*   __restrict__ eidx,
    const f16*   __restrict__ W1F,
    const float* __restrict__ b1,
    const f16*   __restrict__ W2F,
    const float* __restrict__ b2,
    const float* __restrict__ W3,
    const float* __restrict__ b3,
    float* __restrict__ out)
{
    __shared__ __align__(16) f16 sA[M_TILE * 256];
    __shared__ __align__(16) f16 sH1[M_TILE * 256];
    f16* sH2 = sA;

    const int tid = threadIdx.x;
    const int e0  = blockIdx.x * M_TILE;

    // ---- Phase 0: gather emb[col]||emb[row] -> sA (f16, swizzled) ----
    if (F16EMB) {
        const int row  = tid >> 2;        // 0..63 node-slot (edge,side)
        const int g    = tid & 3;         // 64B piece within 256B row
        const int m    = row >> 1;
        const int side = row & 1;
        const int node = eidx[side * E_TOTAL + e0 + m];
        const f16_8* src = (const f16_8*)(emb16 + (size_t)node * HDIM + g * 32);
        #pragma unroll
        for (int i = 0; i < 4; ++i) {
            f16_8 v = src[i];
            const int ch = side * 16 + g * 4 + i;
            *(f16_8*)(sA + m * 256 + ((ch ^ (m & 7)) << 3)) = v;
        }
    } else {
        const int m    = tid >> 3;        // 0..31
        const int side = (tid >> 2) & 1;
        const int sub  = tid & 3;
        const int node = eidx[side * E_TOTAL + e0 + m];
        const float4* src = (const float4*)(emb + (size_t)node * HDIM);
        #pragma unroll
        for (int i = 0; i < 8; ++i) {
            const int c4 = sub + 4 * i;
            float4 f = src[c4];
            f16_4 v = { (f16)f.x, (f16)f.y, (f16)f.z, (f16)f.w };
            const int ch  = side * 16 + (c4 >> 1);
            const int off = (c4 & 1) * 4;
            *(f16_4*)(sA + m * 256 + (((ch ^ (m & 7)) << 3) + off)) = v;
        }
    }
    __syncthreads();

    const int wv   = tid >> 6;     // 0..3
    const int lane = tid & 63;
    const int l31  = lane & 31;
    const int lh   = lane >> 5;    // 0/1
    const int arow = l31;          // A-frag row (edge)
    const int asw  = arow & 7;

    f32_16 acc2 = {0.f};   // P2 accumulator, carried across both K-halves

    #pragma unroll
    for (int hh = 0; hh < 2; ++hh) {
        // ---- Phase 1 (half hh): H1[:, hh*256 + wv*64 .. ] ----
        {
            f32_16 acc1[2] = {{0.f}, {0.f}};
            #pragma unroll
            for (int kc = 0; kc < 16; ++kc) {
                const int ch = kc * 2 + lh;
                f16_8 ef = *(const f16_8*)(sA + arow * 256 + ((ch ^ asw) << 3));
                #pragma unroll
                for (int j = 0; j < 2; ++j) {
                    const int nt = hh * 8 + wv * 2 + j;   // global n-tile
                    f16_8 wf = *(const f16_8*)(W1F + (((nt * 16 + kc) * 64 + lane) << 3));
                    acc1[j] = __builtin_amdgcn_mfma_f32_32x32x16_f16(wf, ef, acc1[j], 0, 0, 0);
                }
            }
            // epilogue: lane holds D[wn=4*lh+8*g+i][edge=arow] -> f16_4 (b64) writes
            #pragma unroll
            for (int j = 0; j < 2; ++j) {
                const int nth = wv * 2 + j;                // tile within half
                #pragma unroll
                for (int g = 0; g < 4; ++g) {
                    const int wnh = nth * 32 + lh * 4 + g * 8;   // wn within half
                    const float4 bv = *(const float4*)(b1 + hh * 256 + wnh);
                    f16_4 hv;
                    #pragma unroll
                    for (int i = 0; i < 4; ++i) {
                        float v = acc1[j][g * 4 + i] + ((const float*)&bv)[i];
                        hv[i] = (f16)(v > 0.f ? v : 0.f);
                    }
                    const int ch  = wnh >> 3;
                    const int off = wnh & 7;               // = lh*4, 8B aligned
                    *(f16_4*)(sH1 + arow * 256 + (((ch ^ asw) << 3) + off)) = hv;
                }
            }
        }
        __syncthreads();   // sH1 half ready

        // ---- Phase 2 (half hh): acc2 += H1half @ W2[hh*256.., wv*32..] ----
        {
            #pragma unroll
            for (int kc = 0; kc < 16; ++kc) {
                const int ch = kc * 2 + lh;
                f16_8 ef = *(const f16_8*)(sH1 + arow * 256 + ((ch ^ asw) << 3));
                f16_8 wf = *(const f16_8*)(W2F + (((wv * 32 + hh * 16 + kc) * 64 + lane) << 3));
                acc2 = __builtin_amdgcn_mfma_f32_32x32x16_f16(wf, ef, acc2, 0, 0, 0);
            }
        }
        __syncthreads();   // done reading sH1 half (next hh overwrites it)
    }

    // ---- Phase 2 epilogue -> sH2 [32][128] (overlays sA; all sA reads done) ----
    {
        #pragma unroll
        for (int g = 0; g < 4; ++g) {
            const int wn = wv * 32 + lh * 4 + g * 8;
            const float4 bv = *(const float4*)(b2 + wn);
            f16_4 hv;
            #pragma unroll
            for (int i = 0; i < 4; ++i) {
                float v = acc2[g * 4 + i] + ((const float*)&bv)[i];
                hv[i] = (f16)(v > 0.f ? v : 0.f);
            }
            const int ch  = wn >> 3;
            const int off = wn & 7;
            *(f16_4*)(sH2 + arow * 128 + (((ch ^ asw) << 3) + off)) = hv;
        }
    }
    __syncthreads();

    // ---- Phase 3: logit = H2 @ W3 + b3 ; sigmoid ----
    {
        const int m = tid >> 3;   // edge 0..31
        const int j = tid & 7;    // 16-k slice
        const int c0 = (2 * j)     ^ (m & 7);
        const int c1 = (2 * j + 1) ^ (m & 7);
        f16_8 a = *(const f16_8*)(sH2 + m * 128 + (c0 << 3));
        f16_8 b = *(const f16_8*)(sH2 + m * 128 + (c1 << 3));
        const float4* w3v = (const float4*)(W3 + j * 16);
        float4 w0 = w3v[0], w1 = w3v[1], w2 = w3v[2], w3 = w3v[3];
        float s = 0.f;
        s += (float)a[0]*w0.x + (float)a[1]*w0.y + (float)a[2]*w0.z + (float)a[3]*w0.w;
        s += (float)a[4]*w1.x + (float)a[5]*w1.y + (float)a[6]*w1.z + (float)a[7]*w1.w;
        s += (float)b[0]*w2.x + (float)b[1]*w2.y + (float)b[2]*w2.z + (float)b[3]*w2.w;
        s += (float)b[4]*w3.x + (float)b[5]*w3.y + (float)b[6]*w3.z + (float)b[7]*w3.w;
        s += __shfl_xor(s, 1);
        s += __shfl_xor(s, 2);
        s += __shfl_xor(s, 4);
        if (j == 0) {
            const float logit = s + b3[0];
            out[e0 + m] = 1.0f / (1.0f + __expf(-logit));
        }
    }
}

extern "C" void kernel_launch(void* const* d_in, const int* in_sizes, int n_in,
                              void* d_out, int out_size, void* d_ws, size_t ws_size,
                              hipStream_t stream) {
    const float* emb  = (const float*)d_in[0];
    const int*   eidx = (const int*)d_in[1];
    const float* W1   = (const float*)d_in[2];
    const float* b1   = (const float*)d_in[3];
    const float* W2   = (const float*)d_in[4];
    const float* b2   = (const float*)d_in[5];
    const float* W3   = (const float*)d_in[6];
    const float* b3   = (const float*)d_in[7];
    float* out = (float*)d_out;

    const size_t wbytes   = (size_t)(K1 * N1 + N1 * N2) * sizeof(f16);   // 384 KB
    const size_t embbytes = (size_t)100000 * HDIM * sizeof(f16);         // 25.6 MB

    f16* W1F = (f16*)d_ws;
    f16* W2F = W1F + K1 * N1;

    const int prep_total = K1 * N1 + N1 * N2;
    prep_weights<<<(prep_total + 255) / 256, 256, 0, stream>>>(W1, W2, W1F, W2F);

    if (ws_size >= wbytes + embbytes) {
        f16* emb16 = W2F + N1 * N2;
        const int cvt_threads = 100000 * HDIM / 4;   // 3.2M
        prep_emb<<<cvt_threads / 256, 256, 0, stream>>>(emb, emb16);
        edge_mlp_kernel<true><<<E_TOTAL / M_TILE, BLOCK, 0, stream>>>(
            emb, emb16, eidx, W1F, b1, W2F, b2, W3, b3, out);
    } else {
        edge_mlp_kernel<false><<<E_TOTAL / M_TILE, BLOCK, 0, stream>>>(
            emb, (const f16*)nullptr, eidx, W1F, b1, W2F, b2, W3, b3, out);
    }
}

// Round 6
// 621.198 us; speedup vs baseline: 1.9111x; 1.9111x over previous
//
#include <hip/hip_runtime.h>
#include <math.h>

#define E_TOTAL   1000000
#define HDIM      128
#define K1        256   // 2H
#define N1        512   // 4H
#define N2        128   // H
#define M_TILE    64
#define BLOCK     512

typedef _Float16 f16;
typedef _Float16 f16_4  __attribute__((ext_vector_type(4)));
typedef _Float16 f16_8  __attribute__((ext_vector_type(8)));
typedef float    f32_16 __attribute__((ext_vector_type(16)));

// ---------------- prep kernels ----------------
// 32x32x16 fragment packing (A/B frag: lane l holds [row=l&31][k=(l>>5)*8+v]):
// W1F[nt(16)][kc(16)][lane(64)][v(8)] = W1[k=kc*16+(l>>5)*8+v][n=nt*32+(l&31)]
// W2F[nt(4)][kcg(32)][lane(64)][v(8)] = W2[k=kcg*16+(l>>5)*8+v][n=nt*32+(l&31)]
__global__ void prep_weights(const float* __restrict__ W1, const float* __restrict__ W2,
                             f16* __restrict__ W1F, f16* __restrict__ W2F) {
    int t = blockIdx.x * blockDim.x + threadIdx.x;
    const int total1 = K1 * N1;           // 131072
    const int total2 = N1 * N2;           // 65536
    if (t < total1) {
        int v    = t & 7;
        int lane = (t >> 3) & 63;
        int kc   = (t >> 9) & 15;
        int nt   = t >> 13;
        int k = kc * 16 + (lane >> 5) * 8 + v;
        int n = nt * 32 + (lane & 31);
        W1F[t] = (f16)W1[k * N1 + n];
    } else if (t < total1 + total2) {
        int u = t - total1;
        int v    = u & 7;
        int lane = (u >> 3) & 63;
        int kcg  = (u >> 9) & 31;
        int nt   = u >> 14;
        int k = kcg * 16 + (lane >> 5) * 8 + v;
        int n = nt * 32 + (lane & 31);
        W2F[u] = (f16)W2[k * N2 + n];
    }
}

__global__ void prep_emb(const float* __restrict__ emb, f16* __restrict__ emb16) {
    int t = blockIdx.x * blockDim.x + threadIdx.x;   // 3.2M threads, 4 elems each
    float4 f = ((const float4*)emb)[t];
    f16_4 v = { (f16)f.x, (f16)f.y, (f16)f.z, (f16)f.w };
    ((f16_4*)emb16)[t] = v;
}

// ---------------- main kernel ----------------
// 512 threads = 8 waves = (et 0..1) x (wnt 0..3); 64 edges/block.
// H1 in FOUR 128-wide quarters, double-buffered sB[2] so P1(q) and P2(q-1)
// run interleaved (two independent MFMA chains per wave in steady state).
// LDS = sA 32 KB + sB 2x16 KB = 64 KB -> 2 blocks/CU at (512,4) [known-good].
// XOR swizzle at 16B chunks: physical chunk = logical ^ (edge_row & 7).
template <bool F16EMB>
__global__ __launch_bounds__(BLOCK, 4) void edge_mlp_kernel(
    const float* __restrict__ emb,
    const f16*   __restrict__ emb16,
    const int*   __restrict__ eidx,
    const f16*   __restrict__ W1F,
    const float* __restrict__ b1,
    const f16*   __restrict__ W2F,
    const float* __restrict__ b2,
    const float* __restrict__ W3,
    const float* __restrict__ b3,
    float* __restrict__ out)
{
    __shared__ __align__(16) f16 sA[M_TILE * 256];      // 32 KB, reused as sH2
    __shared__ __align__(16) f16 sB[2][M_TILE * 128];   // 2 x 16 KB H1-quarter dbuf
    f16* sH2 = sA;

    const int tid = threadIdx.x;
    const int e0  = blockIdx.x * M_TILE;

    // ---- Phase 0: gather emb[col]||emb[row] -> sA (f16, swizzled) ----
    if (F16EMB) {
        const int row  = tid >> 2;        // 0..127 node-slot (edge,side)
        const int g    = tid & 3;         // 64B piece within 256B row
        const int m    = row >> 1;
        const int side = row & 1;
        const int node = eidx[side * E_TOTAL + e0 + m];
        const f16_8* src = (const f16_8*)(emb16 + (size_t)node * HDIM + g * 32);
        #pragma unroll
        for (int i = 0; i < 4; ++i) {
            f16_8 v = src[i];
            const int ch = side * 16 + g * 4 + i;
            *(f16_8*)(sA + m * 256 + ((ch ^ (m & 7)) << 3)) = v;
        }
    } else {
        const int m    = tid >> 3;        // 0..63
        const int side = (tid >> 2) & 1;
        const int sub  = tid & 3;
        const int node = eidx[side * E_TOTAL + e0 + m];
        const float4* src = (const float4*)(emb + (size_t)node * HDIM);
        #pragma unroll
        for (int i = 0; i < 8; ++i) {
            const int c4 = sub + 4 * i;
            float4 f = src[c4];
            f16_4 v = { (f16)f.x, (f16)f.y, (f16)f.z, (f16)f.w };
            const int ch  = side * 16 + (c4 >> 1);
            const int off = (c4 & 1) * 4;
            *(f16_4*)(sA + m * 256 + (((ch ^ (m & 7)) << 3) + off)) = v;
        }
    }
    __syncthreads();

    const int wv   = tid >> 6;     // 0..7
    const int lane = tid & 63;
    const int l31  = lane & 31;
    const int lh   = lane >> 5;    // 0/1
    const int et   = wv & 1;       // edge half (32 edges)
    const int wnt  = wv >> 1;      // 0..3 n-tile within quarter / P2 n-strip
    const int arow = et * 32 + l31;
    const int asw  = arow & 7;

    f32_16 acc2 = {0.f};   // P2 accumulator, persists across all 4 quarters

    // ---- Region 0: P1(0) only -> sB[0] ----
    {
        f32_16 acc1 = {0.f};
        const int nt = wnt;                          // quarter 0, n-tile wnt
        #pragma unroll
        for (int kc = 0; kc < 16; ++kc) {
            const int ch = kc * 2 + lh;
            f16_8 ef = *(const f16_8*)(sA + arow * 256 + ((ch ^ asw) << 3));
            f16_8 wf = *(const f16_8*)(W1F + (((nt * 16 + kc) * 64 + lane) << 3));
            acc1 = __builtin_amdgcn_mfma_f32_32x32x16_f16(wf, ef, acc1, 0, 0, 0);
        }
        #pragma unroll
        for (int g = 0; g < 4; ++g) {
            const int wnl = wnt * 32 + lh * 4 + g * 8;
            const float4 bv = *(const float4*)(b1 + wnl);   // quarter 0
            f16_4 hv;
            #pragma unroll
            for (int i = 0; i < 4; ++i) {
                float v = acc1[g * 4 + i] + ((const float*)&bv)[i];
                hv[i] = (f16)(v > 0.f ? v : 0.f);
            }
            const int ch  = wnl >> 3;
            const int off = wnl & 7;
            *(f16_4*)(&sB[0][0] + arow * 128 + (((ch ^ asw) << 3) + off)) = hv;
        }
    }
    __syncthreads();

    // ---- Regions 1..3: P1(q) -> sB[q&1] interleaved with P2(q-1) <- sB[(q-1)&1] ----
    #pragma unroll
    for (int q = 1; q < 4; ++q) {
        f32_16 acc1 = {0.f};
        const int nt = q * 4 + wnt;
        const f16* bprev = &sB[(q - 1) & 1][0];
        #pragma unroll
        for (int kc = 0; kc < 16; ++kc) {
            const int ch = kc * 2 + lh;
            f16_8 ef = *(const f16_8*)(sA + arow * 256 + ((ch ^ asw) << 3));
            f16_8 wf = *(const f16_8*)(W1F + (((nt * 16 + kc) * 64 + lane) << 3));
            acc1 = __builtin_amdgcn_mfma_f32_32x32x16_f16(wf, ef, acc1, 0, 0, 0);
            if (kc < 8) {
                const int kcg = (q - 1) * 8 + kc;            // global k-chunk
                f16_8 ef2 = *(const f16_8*)(bprev + arow * 128 + ((ch ^ asw) << 3));
                f16_8 wf2 = *(const f16_8*)(W2F + (((wnt * 32 + kcg) * 64 + lane) << 3));
                acc2 = __builtin_amdgcn_mfma_f32_32x32x16_f16(wf2, ef2, acc2, 0, 0, 0);
            }
        }
        // P1(q) epilogue -> sB[q&1]
        f16* bcur = &sB[q & 1][0];
        #pragma unroll
        for (int g = 0; g < 4; ++g) {
            const int wnl = wnt * 32 + lh * 4 + g * 8;
            const float4 bv = *(const float4*)(b1 + q * 128 + wnl);
            f16_4 hv;
            #pragma unroll
            for (int i = 0; i < 4; ++i) {
                float v = acc1[g * 4 + i] + ((const float*)&bv)[i];
                hv[i] = (f16)(v > 0.f ? v : 0.f);
            }
            const int ch  = wnl >> 3;
            const int off = wnl & 7;
            *(f16_4*)(bcur + arow * 128 + (((ch ^ asw) << 3) + off)) = hv;
        }
        __syncthreads();
    }

    // ---- Final P2(3) <- sB[1] ----
    {
        const f16* bprev = &sB[1][0];
        #pragma unroll
        for (int kc = 0; kc < 8; ++kc) {
            const int ch = kc * 2 + lh;
            const int kcg = 24 + kc;
            f16_8 ef2 = *(const f16_8*)(bprev + arow * 128 + ((ch ^ asw) << 3));
            f16_8 wf2 = *(const f16_8*)(W2F + (((wnt * 32 + kcg) * 64 + lane) << 3));
            acc2 = __builtin_amdgcn_mfma_f32_32x32x16_f16(wf2, ef2, acc2, 0, 0, 0);
        }
    }

    // ---- P2 epilogue -> sH2 [64][128] (overlays sA; last sA reads were in
    //      region 3's P1, which all waves completed before region-3 barrier) ----
    {
        #pragma unroll
        for (int g = 0; g < 4; ++g) {
            const int wn = wnt * 32 + lh * 4 + g * 8;
            const float4 bv = *(const float4*)(b2 + wn);
            f16_4 hv;
            #pragma unroll
            for (int i = 0; i < 4; ++i) {
                float v = acc2[g * 4 + i] + ((const float*)&bv)[i];
                hv[i] = (f16)(v > 0.f ? v : 0.f);
            }
            const int ch  = wn >> 3;
            const int off = wn & 7;
            *(f16_4*)(sH2 + arow * 128 + (((ch ^ asw) << 3) + off)) = hv;
        }
    }
    __syncthreads();

    // ---- Phase 3: logit = H2 @ W3 + b3 ; sigmoid ----
    {
        const int m = tid >> 3;   // edge 0..63
        const int j = tid & 7;    // 16-k slice
        const int c0 = (2 * j)     ^ (m & 7);
        const int c1 = (2 * j + 1) ^ (m & 7);
        f16_8 a = *(const f16_8*)(sH2 + m * 128 + (c0 << 3));
        f16_8 b = *(const f16_8*)(sH2 + m * 128 + (c1 << 3));
        const float4* w3v = (const float4*)(W3 + j * 16);
        float4 w0 = w3v[0], w1 = w3v[1], w2 = w3v[2], w3 = w3v[3];
        float s = 0.f;
        s += (float)a[0]*w0.x + (float)a[1]*w0.y + (float)a[2]*w0.z + (float)a[3]*w0.w;
        s += (float)a[4]*w1.x + (float)a[5]*w1.y + (float)a[6]*w1.z + (float)a[7]*w1.w;
        s += (float)b[0]*w2.x + (float)b[1]*w2.y + (float)b[2]*w2.z + (float)b[3]*w2.w;
        s += (float)b[4]*w3.x + (float)b[5]*w3.y + (float)b[6]*w3.z + (float)b[7]*w3.w;
        s += __shfl_xor(s, 1);
        s += __shfl_xor(s, 2);
        s += __shfl_xor(s, 4);
        if (j == 0) {
            const float logit = s + b3[0];
            out[e0 + m] = 1.0f / (1.0f + __expf(-logit));
        }
    }
}

extern "C" void kernel_launch(void* const* d_in, const int* in_sizes, int n_in,
                              void* d_out, int out_size, void* d_ws, size_t ws_size,
                              hipStream_t stream) {
    const float* emb  = (const float*)d_in[0];
    const int*   eidx = (const int*)d_in[1];
    const float* W1   = (const float*)d_in[2];
    const float* b1   = (const float*)d_in[3];
    const float* W2   = (const float*)d_in[4];
    const float* b2   = (const float*)d_in[5];
    const float* W3   = (const float*)d_in[6];
    const float* b3   = (const float*)d_in[7];
    float* out = (float*)d_out;

    const size_t wbytes   = (size_t)(K1 * N1 + N1 * N2) * sizeof(f16);   // 384 KB
    const size_t embbytes = (size_t)100000 * HDIM * sizeof(f16);         // 25.6 MB

    f16* W1F = (f16*)d_ws;
    f16* W2F = W1F + K1 * N1;

    const int prep_total = K1 * N1 + N1 * N2;
    prep_weights<<<(prep_total + 255) / 256, 256, 0, stream>>>(W1, W2, W1F, W2F);

    if (ws_size >= wbytes + embbytes) {
        f16* emb16 = W2F + N1 * N2;
        const int cvt_threads = 100000 * HDIM / 4;   // 3.2M
        prep_emb<<<cvt_threads / 256, 256, 0, stream>>>(emb, emb16);
        edge_mlp_kernel<true><<<E_TOTAL / M_TILE, BLOCK, 0, stream>>>(
            emb, emb16, eidx, W1F, b1, W2F, b2, W3, b3, out);
    } else {
        edge_mlp_kernel<false><<<E_TOTAL / M_TILE, BLOCK, 0, stream>>>(
            emb, (const f16*)nullptr, eidx, W1F, b1, W2F, b2, W3, b3, out);
    }
}

// Round 7
// 616.364 us; speedup vs baseline: 1.9261x; 1.0078x over previous
//
#include <hip/hip_runtime.h>
#include <math.h>

#define E_TOTAL   1000000
#define HDIM      128
#define K1        256   // 2H
#define N1        512   // 4H
#define N2        128   // H
#define M_TILE    64
#define BLOCK     512

typedef _Float16 f16;
typedef _Float16 f16_4  __attribute__((ext_vector_type(4)));
typedef _Float16 f16_8  __attribute__((ext_vector_type(8)));
typedef float    f32_16 __attribute__((ext_vector_type(16)));

// ---------------- prep kernels ----------------
// 32x32x16 fragment packing (A/B frag: lane l holds [row=l&31][k=(l>>5)*8+v]):
// W1F[nt(16)][kc(16)][lane(64)][v(8)] = W1[k=kc*16+(l>>5)*8+v][n=nt*32+(l&31)]
// W2F[nt(4)][kcg(32)][lane(64)][v(8)] = W2[k=kcg*16+(l>>5)*8+v][n=nt*32+(l&31)]
__global__ void prep_weights(const float* __restrict__ W1, const float* __restrict__ W2,
                             f16* __restrict__ W1F, f16* __restrict__ W2F) {
    int t = blockIdx.x * blockDim.x + threadIdx.x;
    const int total1 = K1 * N1;           // 131072
    const int total2 = N1 * N2;           // 65536
    if (t < total1) {
        int v    = t & 7;
        int lane = (t >> 3) & 63;
        int kc   = (t >> 9) & 15;
        int nt   = t >> 13;
        int k = kc * 16 + (lane >> 5) * 8 + v;
        int n = nt * 32 + (lane & 31);
        W1F[t] = (f16)W1[k * N1 + n];
    } else if (t < total1 + total2) {
        int u = t - total1;
        int v    = u & 7;
        int lane = (u >> 3) & 63;
        int kcg  = (u >> 9) & 31;
        int nt   = u >> 14;
        int k = kcg * 16 + (lane >> 5) * 8 + v;
        int n = nt * 32 + (lane & 31);
        W2F[u] = (f16)W2[k * N2 + n];
    }
}

__global__ void prep_emb(const float* __restrict__ emb, f16* __restrict__ emb16) {
    int t = blockIdx.x * blockDim.x + threadIdx.x;   // 3.2M threads, 4 elems each
    float4 f = ((const float4*)emb)[t];
    f16_4 v = { (f16)f.x, (f16)f.y, (f16)f.z, (f16)f.w };
    ((f16_4*)emb16)[t] = v;
}

// ---------------- main kernel ----------------
// R6 pipeline (quarters + sB dbuf) with ALL LDS in MFMA A-frag layout:
//   sAF [et(2)][kc(16)][lane(64)][8]  = 32 KB  (gathered edges; overlaid by sH2F)
//   sBF [buf(2)][et(2)][kl(8)][lane(64)][8] = 2 x 16 KB (H1-quarter dbuf)
//   sH2F[et(2)][kl(8)][lane(64)][8]   = 16 KB  (overlays sAF)
// All ds_read_b128 are lane-linear (conflict-free); epilogue/gather writes map
// 8 lanes -> 8 distinct 16B bank slots per phase (conflict-free).
// 512 threads = 8 waves = (et 0..1) x (wnt 0..3); 64 edges/block.
// LDS 64 KB -> 2 blocks/CU at (512,4) [known-good envelope].
template <bool F16EMB>
__global__ __launch_bounds__(BLOCK, 4) void edge_mlp_kernel(
    const float* __restrict__ emb,
    const f16*   __restrict__ emb16,
    const int*   __restrict__ eidx,
    const f16*   __restrict__ W1F,
    const float* __restrict__ b1,
    const f16*   __restrict__ W2F,
    const float* __restrict__ b2,
    const float* __restrict__ W3,
    const float* __restrict__ b3,
    float* __restrict__ out)
{
    __shared__ __align__(16) f16 sAF[2 * 16 * 64 * 8];      // 32 KB
    __shared__ __align__(16) f16 sBF[2][2 * 8 * 64 * 8];    // 2 x 16 KB
    f16* sH2F = sAF;                                        // 16 KB overlay

    const int tid = threadIdx.x;
    const int e0  = blockIdx.x * M_TILE;

    // ---- Phase 0: gather emb[col]||emb[row] -> sAF (fragment layout) ----
    // thread: m=tid>>3 (edge), side=(tid>>2)&1, sub=tid&3 -> g = side*8+sub*2+{0,1}
    // piece (m, kc=g, lh): 8 f16 at sAF[((met*16+g)*64 + lh*32 + m31)*8]
    {
        const int m    = tid >> 3;
        const int side = (tid >> 2) & 1;
        const int sub  = tid & 3;
        const int met  = m >> 5;
        const int m31  = m & 31;
        const int node = eidx[side * E_TOTAL + e0 + m];
        if (F16EMB) {
            const f16* src = emb16 + (size_t)node * HDIM;
            #pragma unroll
            for (int j = 0; j < 2; ++j) {
                const int g = side * 8 + sub * 2 + j;
                const int koff = (sub * 2 + j) * 16;       // within node row
                #pragma unroll
                for (int lh = 0; lh < 2; ++lh) {
                    f16_8 v = *(const f16_8*)(src + koff + lh * 8);
                    *(f16_8*)(sAF + (((met * 16 + g) * 64 + lh * 32 + m31) << 3)) = v;
                }
            }
        } else {
            const float* src = emb + (size_t)node * HDIM;
            #pragma unroll
            for (int j = 0; j < 2; ++j) {
                const int g = side * 8 + sub * 2 + j;
                const int koff = (sub * 2 + j) * 16;
                #pragma unroll
                for (int lh = 0; lh < 2; ++lh) {
                    float4 fa = *(const float4*)(src + koff + lh * 8);
                    float4 fb = *(const float4*)(src + koff + lh * 8 + 4);
                    f16_8 v = { (f16)fa.x, (f16)fa.y, (f16)fa.z, (f16)fa.w,
                                (f16)fb.x, (f16)fb.y, (f16)fb.z, (f16)fb.w };
                    *(f16_8*)(sAF + (((met * 16 + g) * 64 + lh * 32 + m31) << 3)) = v;
                }
            }
        }
    }
    __syncthreads();

    const int wv   = tid >> 6;     // 0..7
    const int lane = tid & 63;
    const int l31  = lane & 31;
    const int lh   = lane >> 5;    // 0/1
    const int et   = wv & 1;       // edge half (32 edges)
    const int wnt  = wv >> 1;      // 0..3 n-tile within quarter / P2 n-strip

    f32_16 acc2 = {0.f};   // P2 accumulator, persists across all 4 quarters

    // ---- Region 0: P1(0) only -> sBF[0] ----
    {
        f32_16 acc1 = {0.f};
        const int nt = wnt;                          // quarter 0, n-tile wnt
        #pragma unroll
        for (int kc = 0; kc < 16; ++kc) {
            f16_8 ef = *(const f16_8*)(sAF + (((et * 16 + kc) * 64 + lane) << 3));
            f16_8 wf = *(const f16_8*)(W1F + (((nt * 16 + kc) * 64 + lane) << 3));
            acc1 = __builtin_amdgcn_mfma_f32_32x32x16_f16(wf, ef, acc1, 0, 0, 0);
        }
        // epilogue: value (edge=et*32+l31, n1q = wnt*32+lh*4+g*8+i) -> frag write
        f16* bcur = &sBF[0][0];
        #pragma unroll
        for (int g = 0; g < 4; ++g) {
            const int wnl = wnt * 32 + lh * 4 + g * 8;
            const float4 bv = *(const float4*)(b1 + wnl);   // quarter 0
            f16_4 hv;
            #pragma unroll
            for (int i = 0; i < 4; ++i) {
                float v = acc1[g * 4 + i] + ((const float*)&bv)[i];
                hv[i] = (f16)(v > 0.f ? v : 0.f);
            }
            const int kl = wnt * 2 + (g >> 1);
            *(f16_4*)(bcur + ((((et * 8 + kl) * 64 + (g & 1) * 32 + l31) << 3) + lh * 4)) = hv;
        }
    }
    __syncthreads();

    // ---- Regions 1..3: P1(q) -> sBF[q&1] interleaved with P2(q-1) <- sBF[(q-1)&1] ----
    #pragma unroll
    for (int q = 1; q < 4; ++q) {
        f32_16 acc1 = {0.f};
        const int nt = q * 4 + wnt;
        const f16* bprev = &sBF[(q - 1) & 1][0];
        #pragma unroll
        for (int kc = 0; kc < 16; ++kc) {
            f16_8 ef = *(const f16_8*)(sAF + (((et * 16 + kc) * 64 + lane) << 3));
            f16_8 wf = *(const f16_8*)(W1F + (((nt * 16 + kc) * 64 + lane) << 3));
            acc1 = __builtin_amdgcn_mfma_f32_32x32x16_f16(wf, ef, acc1, 0, 0, 0);
            if (kc < 8) {
                const int kcg = (q - 1) * 8 + kc;            // global k-chunk for W2
                f16_8 ef2 = *(const f16_8*)(bprev + (((et * 8 + kc) * 64 + lane) << 3));
                f16_8 wf2 = *(const f16_8*)(W2F + (((wnt * 32 + kcg) * 64 + lane) << 3));
                acc2 = __builtin_amdgcn_mfma_f32_32x32x16_f16(wf2, ef2, acc2, 0, 0, 0);
            }
        }
        // P1(q) epilogue -> sBF[q&1]
        f16* bcur = &sBF[q & 1][0];
        #pragma unroll
        for (int g = 0; g < 4; ++g) {
            const int wnl = wnt * 32 + lh * 4 + g * 8;
            const float4 bv = *(const float4*)(b1 + q * 128 + wnl);
            f16_4 hv;
            #pragma unroll
            for (int i = 0; i < 4; ++i) {
                float v = acc1[g * 4 + i] + ((const float*)&bv)[i];
                hv[i] = (f16)(v > 0.f ? v : 0.f);
            }
            const int kl = wnt * 2 + (g >> 1);
            *(f16_4*)(bcur + ((((et * 8 + kl) * 64 + (g & 1) * 32 + l31) << 3) + lh * 4)) = hv;
        }
        __syncthreads();
    }

    // ---- Final P2(3) <- sBF[1] ----
    {
        const f16* bprev = &sBF[1][0];
        #pragma unroll
        for (int kc = 0; kc < 8; ++kc) {
            const int kcg = 24 + kc;
            f16_8 ef2 = *(const f16_8*)(bprev + (((et * 8 + kc) * 64 + lane) << 3));
            f16_8 wf2 = *(const f16_8*)(W2F + (((wnt * 32 + kcg) * 64 + lane) << 3));
            acc2 = __builtin_amdgcn_mfma_f32_32x32x16_f16(wf2, ef2, acc2, 0, 0, 0);
        }
    }

    // ---- P2 epilogue -> sH2F (fragment layout, overlays sAF; all sAF reads
    //      completed before the q=3 barrier) ----
    {
        #pragma unroll
        for (int g = 0; g < 4; ++g) {
            const int wn = wnt * 32 + lh * 4 + g * 8;
            const float4 bv = *(const float4*)(b2 + wn);
            f16_4 hv;
            #pragma unroll
            for (int i = 0; i < 4; ++i) {
                float v = acc2[g * 4 + i] + ((const float*)&bv)[i];
                hv[i] = (f16)(v > 0.f ? v : 0.f);
            }
            const int kl = wnt * 2 + (g >> 1);
            *(f16_4*)(sH2F + ((((et * 8 + kl) * 64 + (g & 1) * 32 + l31) << 3) + lh * 4)) = hv;
        }
    }
    __syncthreads();

    // ---- Phase 3: logit = H2 @ W3 + b3 ; sigmoid ----
    // thread: m=tid>>3 (edge), j=tid&7 (16-k chunk). H2[m][j*16+lh'*8+v] is at
    // sH2F[((met*8+j)*64 + lh'*32 + m31)*8 + v].
    {
        const int m   = tid >> 3;
        const int j   = tid & 7;
        const int met = m >> 5;
        const int m31 = m & 31;
        f16_8 a = *(const f16_8*)(sH2F + (((met * 8 + j) * 64 + m31) << 3));
        f16_8 b = *(const f16_8*)(sH2F + (((met * 8 + j) * 64 + 32 + m31) << 3));
        const float4* w3v = (const float4*)(W3 + j * 16);
        float4 w0 = w3v[0], w1 = w3v[1], w2 = w3v[2], w3 = w3v[3];
        float s = 0.f;
        s += (float)a[0]*w0.x + (float)a[1]*w0.y + (float)a[2]*w0.z + (float)a[3]*w0.w;
        s += (float)a[4]*w1.x + (float)a[5]*w1.y + (float)a[6]*w1.z + (float)a[7]*w1.w;
        s += (float)b[0]*w2.x + (float)b[1]*w2.y + (float)b[2]*w2.z + (float)b[3]*w2.w;
        s += (float)b[4]*w3.x + (float)b[5]*w3.y + (float)b[6]*w3.z + (float)b[7]*w3.w;
        s += __shfl_xor(s, 1);
        s += __shfl_xor(s, 2);
        s += __shfl_xor(s, 4);
        if (j == 0) {
            const float logit = s + b3[0];
            out[e0 + m] = 1.0f / (1.0f + __expf(-logit));
        }
    }
}

extern "C" void kernel_launch(void* const* d_in, const int* in_sizes, int n_in,
                              void* d_out, int out_size, void* d_ws, size_t ws_size,
                              hipStream_t stream) {
    const float* emb  = (const float*)d_in[0];
    const int*   eidx = (const int*)d_in[1];
    const float* W1   = (const float*)d_in[2];
    const float* b1   = (const float*)d_in[3];
    const float* W2   = (const float*)d_in[4];
    const float* b2   = (const float*)d_in[5];
    const float* W3   = (const float*)d_in[6];
    const float* b3   = (const float*)d_in[7];
    float* out = (float*)d_out;

    const size_t wbytes   = (size_t)(K1 * N1 + N1 * N2) * sizeof(f16);   // 384 KB
    const size_t embbytes = (size_t)100000 * HDIM * sizeof(f16);         // 25.6 MB

    f16* W1F = (f16*)d_ws;
    f16* W2F = W1F + K1 * N1;

    const int prep_total = K1 * N1 + N1 * N2;
    prep_weights<<<(prep_total + 255) / 256, 256, 0, stream>>>(W1, W2, W1F, W2F);

    if (ws_size >= wbytes + embbytes) {
        f16* emb16 = W2F + N1 * N2;
        const int cvt_threads = 100000 * HDIM / 4;   // 3.2M
        prep_emb<<<cvt_threads / 256, 256, 0, stream>>>(emb, emb16);
        edge_mlp_kernel<true><<<E_TOTAL / M_TILE, BLOCK, 0, stream>>>(
            emb, emb16, eidx, W1F, b1, W2F, b2, W3, b3, out);
    } else {
        edge_mlp_kernel<false><<<E_TOTAL / M_TILE, BLOCK, 0, stream>>>(
            emb, (const f16*)nullptr, eidx, W1F, b1, W2F, b2, W3, b3, out);
    }
}